// Round 1
// baseline (1116.083 us; speedup 1.0000x reference)
//
#include <hip/hip_runtime.h>
#include <math.h>

#define BLOCK 256
#define TM    1024
#define NB    16
#define NN_   4096
#define MM_   4096
#define NITER 5

// ws layout (float offsets)
#define OFF_STATS 0      // 16*4  : sum_x, sum_y, sum_z, sum_ss per batch
#define OFF_T     64     // 16*16 : R[9] row-major [e][d], t[3], scale
#define OFF_PART  320    // 256*12: NN per-block partial sums
#define OFF_PA    3392   // 256   : src->tgt rowmin partial sums
#define OFF_PB    3648   // 256   : tgt->src colmin partial sums

// ---------------------------------------------------------------- init ----
__global__ __launch_bounds__(BLOCK) void icp_init(const float* __restrict__ src,
                                                  float* __restrict__ ws) {
  int b = blockIdx.x, tid = threadIdx.x;
  const float* sb = src + (size_t)b * NN_ * 3;
  float sx = 0.f, sy = 0.f, sz = 0.f, ss = 0.f;
  for (int n = tid; n < NN_; n += BLOCK) {
    float x = sb[3*n], y = sb[3*n+1], z = sb[3*n+2];
    sx += x; sy += y; sz += z;
    ss += fmaf(x, x, fmaf(y, y, z*z));
  }
  __shared__ float red[16];
  for (int m = 32; m; m >>= 1) {
    sx += __shfl_xor(sx, m); sy += __shfl_xor(sy, m);
    sz += __shfl_xor(sz, m); ss += __shfl_xor(ss, m);
  }
  int wave = tid >> 6;
  if ((tid & 63) == 0) {
    red[wave*4+0] = sx; red[wave*4+1] = sy; red[wave*4+2] = sz; red[wave*4+3] = ss;
  }
  __syncthreads();
  if (tid == 0) {
    for (int w = 1; w < 4; ++w) {
      sx += red[w*4+0]; sy += red[w*4+1]; sz += red[w*4+2]; ss += red[w*4+3];
    }
    float* st = ws + OFF_STATS + b*4;
    st[0] = sx; st[1] = sy; st[2] = sz; st[3] = ss;
    float* T = ws + OFF_T + b*16;
    T[0]=1.f; T[1]=0.f; T[2]=0.f;
    T[3]=0.f; T[4]=1.f; T[5]=0.f;
    T[6]=0.f; T[7]=0.f; T[8]=1.f;
    T[9]=0.f; T[10]=0.f; T[11]=0.f; T[12]=1.f;
  }
}

// ------------------------------------------------------------------ NN ----
// grid (N/BLOCK, B). One thread = one source point. Finds argmin_m dist and
// accumulates per-block partials of [t, s (x) t] (12 floats).
__global__ __launch_bounds__(BLOCK) void icp_nn(const float* __restrict__ src,
                                                const float* __restrict__ tgt,
                                                float* __restrict__ ws) {
  __shared__ float4 tile[TM];
  __shared__ float red[4*12];
  int b = blockIdx.y, chunk = blockIdx.x, tid = threadIdx.x;
  int n = chunk * BLOCK + tid;
  const float* sp = src + ((size_t)b * NN_ + n) * 3;
  float sx = sp[0], sy = sp[1], sz = sp[2];
  const float* T = ws + OFF_T + b*16;
  float sc = T[12];
  float px = fmaf(sc, fmaf(T[0], sx, fmaf(T[1], sy, T[2]*sz)), T[9]);
  float py = fmaf(sc, fmaf(T[3], sx, fmaf(T[4], sy, T[5]*sz)), T[10]);
  float pz = fmaf(sc, fmaf(T[6], sx, fmaf(T[7], sy, T[8]*sz)), T[11]);
  float nx = -2.f*px, ny = -2.f*py, nz = -2.f*pz;
  const float* tb = tgt + (size_t)b * MM_ * 3;

  float best = INFINITY;
  int bidx = 0;
  for (int base = 0; base < MM_; base += TM) {
    __syncthreads();
    for (int j = tid; j < TM; j += BLOCK) {
      const float* tp = tb + 3*(base + j);
      float tx = tp[0], ty = tp[1], tz = tp[2];
      tile[j] = make_float4(tx, ty, tz, fmaf(tx, tx, fmaf(ty, ty, tz*tz)));
    }
    __syncthreads();
#pragma unroll 8
    for (int j = 0; j < TM; ++j) {
      float4 t = tile[j];
      float v = fmaf(nx, t.x, fmaf(ny, t.y, fmaf(nz, t.z, t.w)));
      if (v < best) { best = v; bidx = base + j; }
    }
  }
  // gather correspondence (uses ORIGINAL source for H)
  const float* tp = tb + 3*bidx;
  float tx = tp[0], ty = tp[1], tz = tp[2];
  float acc[12] = {tx, ty, tz,
                   sx*tx, sx*ty, sx*tz,
                   sy*tx, sy*ty, sy*tz,
                   sz*tx, sz*ty, sz*tz};
#pragma unroll
  for (int c = 0; c < 12; ++c)
    for (int m = 32; m; m >>= 1) acc[c] += __shfl_xor(acc[c], m);
  int wave = tid >> 6;
  if ((tid & 63) == 0) {
#pragma unroll
    for (int c = 0; c < 12; ++c) red[wave*12 + c] = acc[c];
  }
  __syncthreads();
  if (tid < 12) {
    float s = red[tid] + red[12+tid] + red[24+tid] + red[36+tid];
    ws[OFF_PART + (b*16 + chunk)*12 + tid] = s;
  }
}

// ------------------------------------------------------------- Umeyama ----
__global__ __launch_bounds__(64) void icp_umeyama(float* __restrict__ ws) {
  int b = blockIdx.x, tid = threadIdx.x;
  __shared__ double sums[12];
  if (tid < 12) {
    double s = 0.0;
    for (int j = 0; j < 16; ++j)
      s += (double)ws[OFF_PART + (b*16 + j)*12 + tid];
    sums[tid] = s;
  }
  __syncthreads();
  if (tid != 0) return;

  const float* st = ws + OFF_STATS + b*4;
  const double N = (double)NN_;
  double mus[3] = {st[0]/N, st[1]/N, st[2]/N};
  double var_src = (double)st[3] - N*(mus[0]*mus[0] + mus[1]*mus[1] + mus[2]*mus[2]);
  double mut[3] = {sums[0]/N, sums[1]/N, sums[2]/N};
  double H[3][3];
  for (int d = 0; d < 3; ++d)
    for (int e = 0; e < 3; ++e)
      H[d][e] = sums[3 + 3*d + e] - N*mus[d]*mut[e];

  // A = H^T H, Jacobi eigendecomposition -> V, lambda
  double A[3][3];
  for (int i = 0; i < 3; ++i)
    for (int j = 0; j < 3; ++j)
      A[i][j] = H[0][i]*H[0][j] + H[1][i]*H[1][j] + H[2][i]*H[2][j];
  double V[3][3] = {{1,0,0},{0,1,0},{0,0,1}};
  const int PP[3] = {0,0,1}, QQ[3] = {1,2,2};
  for (int sweep = 0; sweep < 14; ++sweep) {
    for (int r = 0; r < 3; ++r) {
      int p = PP[r], q = QQ[r];
      double apq = A[p][q];
      if (fabs(apq) < 1e-300) continue;
      double tau = (A[q][q] - A[p][p]) / (2.0*apq);
      double tt = (tau >= 0.0 ? 1.0 : -1.0) / (fabs(tau) + sqrt(1.0 + tau*tau));
      double c = 1.0 / sqrt(1.0 + tt*tt), s = tt*c;
      for (int k = 0; k < 3; ++k) { double akp=A[k][p], akq=A[k][q];
        A[k][p]=c*akp - s*akq; A[k][q]=s*akp + c*akq; }
      for (int k = 0; k < 3; ++k) { double apk=A[p][k], aqk=A[q][k];
        A[p][k]=c*apk - s*aqk; A[q][k]=s*apk + c*aqk; }
      for (int k = 0; k < 3; ++k) { double vkp=V[k][p], vkq=V[k][q];
        V[k][p]=c*vkp - s*vkq; V[k][q]=s*vkp + c*vkq; }
    }
  }
  double lam[3] = {A[0][0], A[1][1], A[2][2]};
  int o[3] = {0,1,2};
  if (lam[o[1]] > lam[o[0]]) { int t_=o[0]; o[0]=o[1]; o[1]=t_; }
  if (lam[o[2]] > lam[o[0]]) { int t_=o[0]; o[0]=o[2]; o[2]=t_; }
  if (lam[o[2]] > lam[o[1]]) { int t_=o[1]; o[1]=o[2]; o[2]=t_; }
  double v0[3] = {V[0][o[0]], V[1][o[0]], V[2][o[0]]};
  double v1[3] = {V[0][o[1]], V[1][o[1]], V[2][o[1]]};
  double v2[3] = {V[0][o[2]], V[1][o[2]], V[2][o[2]]};

  double hv0[3], hv1[3], hv2[3];
  for (int d = 0; d < 3; ++d) {
    hv0[d] = H[d][0]*v0[0] + H[d][1]*v0[1] + H[d][2]*v0[2];
    hv1[d] = H[d][0]*v1[0] + H[d][1]*v1[1] + H[d][2]*v1[2];
    hv2[d] = H[d][0]*v2[0] + H[d][1]*v2[1] + H[d][2]*v2[2];
  }
  double S0 = sqrt(hv0[0]*hv0[0] + hv0[1]*hv0[1] + hv0[2]*hv0[2]);
  double u0[3];
  double inv0 = (S0 > 1e-30) ? 1.0/S0 : 0.0;
  u0[0]=hv0[0]*inv0; u0[1]=hv0[1]*inv0; u0[2]=hv0[2]*inv0;
  if (S0 <= 1e-30) { u0[0]=1.0; u0[1]=0.0; u0[2]=0.0; }
  double S1 = sqrt(hv1[0]*hv1[0] + hv1[1]*hv1[1] + hv1[2]*hv1[2]);
  double d01 = u0[0]*hv1[0] + u0[1]*hv1[1] + u0[2]*hv1[2];
  double w1[3] = {hv1[0]-d01*u0[0], hv1[1]-d01*u0[1], hv1[2]-d01*u0[2]};
  double n1 = sqrt(w1[0]*w1[0] + w1[1]*w1[1] + w1[2]*w1[2]);
  double u1[3];
  if (n1 > 1e-30) { u1[0]=w1[0]/n1; u1[1]=w1[1]/n1; u1[2]=w1[2]/n1; }
  else { // pick any unit vector orthogonal to u0
    double ax = fabs(u0[0]);
    double t0[3] = { ax < 0.9 ? 1.0 : 0.0, ax < 0.9 ? 0.0 : 1.0, 0.0 };
    u1[0] = u0[1]*t0[2]-u0[2]*t0[1];
    u1[1] = u0[2]*t0[0]-u0[0]*t0[2];
    u1[2] = u0[0]*t0[1]-u0[1]*t0[0];
    double nn = sqrt(u1[0]*u1[0]+u1[1]*u1[1]+u1[2]*u1[2]);
    u1[0]/=nn; u1[1]/=nn; u1[2]/=nn;
  }
  double u2[3] = {u0[1]*u1[2]-u0[2]*u1[1],
                  u0[2]*u1[0]-u0[0]*u1[2],
                  u0[0]*u1[1]-u0[1]*u1[0]};
  double s2p = u2[0]*hv2[0] + u2[1]*hv2[1] + u2[2]*hv2[2];
  double dV = v0[0]*(v1[1]*v2[2]-v1[2]*v2[1])
            - v0[1]*(v1[0]*v2[2]-v1[2]*v2[0])
            + v0[2]*(v1[0]*v2[1]-v1[1]*v2[0]);
  dV = (dV >= 0.0) ? 1.0 : -1.0;
  double traceS = S0 + S1 + dV * s2p;

  double R[3][3];
  for (int i = 0; i < 3; ++i)
    for (int k = 0; k < 3; ++k)
      R[i][k] = v0[i]*u0[k] + v1[i]*u1[k] + dV*v2[i]*u2[k];

  double scale = traceS / (var_src + 1e-8);
  scale = fmin(fmax(scale, 0.5), 2.0);
  double tv[3];
  for (int e = 0; e < 3; ++e)
    tv[e] = mut[e] - scale*(R[e][0]*mus[0] + R[e][1]*mus[1] + R[e][2]*mus[2]);

  float* T = ws + OFF_T + b*16;
  for (int e = 0; e < 3; ++e)
    for (int d = 0; d < 3; ++d)
      T[3*e + d] = (float)R[e][d];
  T[9]  = (float)tv[0]; T[10] = (float)tv[1]; T[11] = (float)tv[2];
  T[12] = (float)scale;
}

// --------------------------------------------------- final src->tgt -------
__global__ __launch_bounds__(BLOCK) void icp_final_s2t(const float* __restrict__ src,
                                                       const float* __restrict__ tgt,
                                                       float* __restrict__ out,
                                                       float* __restrict__ ws) {
  __shared__ float4 tile[TM];
  __shared__ float red[4];
  int b = blockIdx.y, chunk = blockIdx.x, tid = threadIdx.x;
  int n = chunk * BLOCK + tid;
  const float* sp = src + ((size_t)b * NN_ + n) * 3;
  float sx = sp[0], sy = sp[1], sz = sp[2];
  const float* T = ws + OFF_T + b*16;
  float sc = T[12];
  float px = fmaf(sc, fmaf(T[0], sx, fmaf(T[1], sy, T[2]*sz)), T[9]);
  float py = fmaf(sc, fmaf(T[3], sx, fmaf(T[4], sy, T[5]*sz)), T[10]);
  float pz = fmaf(sc, fmaf(T[6], sx, fmaf(T[7], sy, T[8]*sz)), T[11]);
  float* op = out + 1 + ((size_t)b * NN_ + n) * 3;
  op[0] = px; op[1] = py; op[2] = pz;
  float p2 = fmaf(px, px, fmaf(py, py, pz*pz));
  float nx = -2.f*px, ny = -2.f*py, nz = -2.f*pz;
  const float* tb = tgt + (size_t)b * MM_ * 3;

  float best = INFINITY;
  for (int base = 0; base < MM_; base += TM) {
    __syncthreads();
    for (int j = tid; j < TM; j += BLOCK) {
      const float* tp = tb + 3*(base + j);
      float tx = tp[0], ty = tp[1], tz = tp[2];
      tile[j] = make_float4(tx, ty, tz, fmaf(tx, tx, fmaf(ty, ty, tz*tz)));
    }
    __syncthreads();
#pragma unroll 8
    for (int j = 0; j < TM; ++j) {
      float4 t = tile[j];
      float v = fmaf(nx, t.x, fmaf(ny, t.y, fmaf(nz, t.z, t.w)));
      best = fminf(best, v);
    }
  }
  float rowmin = fmaxf(best + p2, 0.f);
  for (int m = 32; m; m >>= 1) rowmin += __shfl_xor(rowmin, m);
  int wave = tid >> 6;
  if ((tid & 63) == 0) red[wave] = rowmin;
  __syncthreads();
  if (tid == 0)
    ws[OFF_PA + b*16 + chunk] = red[0] + red[1] + red[2] + red[3];
}

// --------------------------------------------------- final tgt->src -------
__global__ __launch_bounds__(BLOCK) void icp_final_t2s(const float* __restrict__ tgt,
                                                       const float* __restrict__ out,
                                                       float* __restrict__ ws) {
  __shared__ float4 tile[TM];
  __shared__ float red[4];
  int b = blockIdx.y, chunk = blockIdx.x, tid = threadIdx.x;
  int m = chunk * BLOCK + tid;
  const float* qp = tgt + ((size_t)b * MM_ + m) * 3;
  float qx = qp[0], qy = qp[1], qz = qp[2];
  float q2 = fmaf(qx, qx, fmaf(qy, qy, qz*qz));
  float nx = -2.f*qx, ny = -2.f*qy, nz = -2.f*qz;
  const float* ab = out + 1 + (size_t)b * NN_ * 3;

  float best = INFINITY;
  for (int base = 0; base < NN_; base += TM) {
    __syncthreads();
    for (int j = tid; j < TM; j += BLOCK) {
      const float* ap = ab + 3*(base + j);
      float ax = ap[0], ay = ap[1], az = ap[2];
      tile[j] = make_float4(ax, ay, az, fmaf(ax, ax, fmaf(ay, ay, az*az)));
    }
    __syncthreads();
#pragma unroll 8
    for (int j = 0; j < TM; ++j) {
      float4 a = tile[j];
      float v = fmaf(nx, a.x, fmaf(ny, a.y, fmaf(nz, a.z, a.w)));
      best = fminf(best, v);
    }
  }
  float colmin = fmaxf(best + q2, 0.f);
  for (int m2 = 32; m2; m2 >>= 1) colmin += __shfl_xor(colmin, m2);
  int wave = tid >> 6;
  if ((tid & 63) == 0) red[wave] = colmin;
  __syncthreads();
  if (tid == 0)
    ws[OFF_PB + b*16 + chunk] = red[0] + red[1] + red[2] + red[3];
}

// ------------------------------------------------------------ finalize ----
__global__ __launch_bounds__(64) void icp_finalize(float* __restrict__ out,
                                                   const float* __restrict__ ws) {
  __shared__ float cham[16];
  int tid = threadIdx.x;
  if (tid < 16) {
    float sa = 0.f, sb = 0.f;
    for (int j = 0; j < 16; ++j) {
      sa += ws[OFF_PA + tid*16 + j];
      sb += ws[OFF_PB + tid*16 + j];
    }
    cham[tid] = sa / (float)NN_ + sb / (float)MM_;
  }
  __syncthreads();
  if (tid == 0) {
    float s = 0.f;
    for (int b2 = 0; b2 < 16; ++b2) s += cham[b2];
    out[0] = s / 16.f;
  }
}

// -------------------------------------------------------------- launch ----
extern "C" void kernel_launch(void* const* d_in, const int* in_sizes, int n_in,
                              void* d_out, int out_size, void* d_ws, size_t ws_size,
                              hipStream_t stream) {
  const float* src = (const float*)d_in[0];
  const float* tgt = (const float*)d_in[1];
  float* out = (float*)d_out;
  float* ws  = (float*)d_ws;

  icp_init<<<NB, BLOCK, 0, stream>>>(src, ws);
  for (int it = 0; it < NITER; ++it) {
    icp_nn<<<dim3(NN_/BLOCK, NB), BLOCK, 0, stream>>>(src, tgt, ws);
    icp_umeyama<<<NB, 64, 0, stream>>>(ws);
  }
  icp_final_s2t<<<dim3(NN_/BLOCK, NB), BLOCK, 0, stream>>>(src, tgt, out, ws);
  icp_final_t2s<<<dim3(MM_/BLOCK, NB), BLOCK, 0, stream>>>(tgt, out, ws);
  icp_finalize<<<1, 64, 0, stream>>>(out, ws);
}

// Round 2
// 395.699 us; speedup vs baseline: 2.8205x; 2.8205x over previous
//
#include <hip/hip_runtime.h>
#include <math.h>

#define BLOCK 256
#define NB    16
#define NN_   4096
#define MM_   4096
#define NITER 5
#define P     4      // points per thread
#define SCH   4      // query chunks (1024 pts each = 256 thr * P)
#define KCH   8      // search-dim chunks
#define TCH   512    // targets per chunk (4096/KCH)

// ws layout (float offsets)
#define OFF_STATS 0        // 16*4
#define OFF_T     64       // 16*16
#define OFF_PART  320      // 16*4*12 = 768 -> ends 1088
#define OFF_CH    1088     // 16
#define OFF_ND    1280     // 16*8*4096 = 524288 -> ends 525568
#define OFF_NI    525568   // 524288 -> ends 1049856
#define OFF_FA    1280     // reuse ND region (finals run after NN)
#define OFF_FB    525568   // reuse NI region

// ---------------------------------------------------------------- init ----
__global__ __launch_bounds__(BLOCK) void icp_init(const float* __restrict__ src,
                                                  float* __restrict__ ws) {
  int b = blockIdx.x, tid = threadIdx.x;
  const float* sb = src + (size_t)b * NN_ * 3;
  float sx = 0.f, sy = 0.f, sz = 0.f, ss = 0.f;
  for (int n = tid; n < NN_; n += BLOCK) {
    float x = sb[3*n], y = sb[3*n+1], z = sb[3*n+2];
    sx += x; sy += y; sz += z;
    ss += fmaf(x, x, fmaf(y, y, z*z));
  }
  __shared__ float red[16];
  for (int m = 32; m; m >>= 1) {
    sx += __shfl_xor(sx, m); sy += __shfl_xor(sy, m);
    sz += __shfl_xor(sz, m); ss += __shfl_xor(ss, m);
  }
  int wave = tid >> 6;
  if ((tid & 63) == 0) {
    red[wave*4+0] = sx; red[wave*4+1] = sy; red[wave*4+2] = sz; red[wave*4+3] = ss;
  }
  __syncthreads();
  if (tid == 0) {
    for (int w = 1; w < 4; ++w) {
      sx += red[w*4+0]; sy += red[w*4+1]; sz += red[w*4+2]; ss += red[w*4+3];
    }
    float* st = ws + OFF_STATS + b*4;
    st[0] = sx; st[1] = sy; st[2] = sz; st[3] = ss;
    float* T = ws + OFF_T + b*16;
    T[0]=1.f; T[1]=0.f; T[2]=0.f;
    T[3]=0.f; T[4]=1.f; T[5]=0.f;
    T[6]=0.f; T[7]=0.f; T[8]=1.f;
    T[9]=0.f; T[10]=0.f; T[11]=0.f; T[12]=1.f;
  }
}

// ---------------------------------------------------------- NN pass 1 -----
// grid (SCH, KCH, B). Each thread: P source points vs one target chunk.
// Writes partial (best dist, best idx) per (point, chunk).
__global__ __launch_bounds__(BLOCK) void icp_nn1(const float* __restrict__ src,
                                                 const float* __restrict__ tgt,
                                                 float* __restrict__ ws) {
  __shared__ float4 tile[TCH];
  int b = blockIdx.z, kc = blockIdx.y, tid = threadIdx.x;
  int n0 = blockIdx.x * (BLOCK * P) + tid;
  const float* T = ws + OFF_T + b*16;
  float sc = T[12];
  float nx[P], ny[P], nz[P];
#pragma unroll
  for (int k = 0; k < P; ++k) {
    const float* sp = src + ((size_t)b * NN_ + n0 + k*BLOCK) * 3;
    float sx = sp[0], sy = sp[1], sz = sp[2];
    float px = fmaf(sc, fmaf(T[0], sx, fmaf(T[1], sy, T[2]*sz)), T[9]);
    float py = fmaf(sc, fmaf(T[3], sx, fmaf(T[4], sy, T[5]*sz)), T[10]);
    float pz = fmaf(sc, fmaf(T[6], sx, fmaf(T[7], sy, T[8]*sz)), T[11]);
    nx[k] = -2.f*px; ny[k] = -2.f*py; nz[k] = -2.f*pz;
  }
  const float* tb = tgt + ((size_t)b * MM_ + kc * TCH) * 3;
  for (int j = tid; j < TCH; j += BLOCK) {
    float tx = tb[3*j], ty = tb[3*j+1], tz = tb[3*j+2];
    tile[j] = make_float4(tx, ty, tz, fmaf(tx, tx, fmaf(ty, ty, tz*tz)));
  }
  __syncthreads();

  float best[P]; int bidx[P];
#pragma unroll
  for (int k = 0; k < P; ++k) { best[k] = INFINITY; bidx[k] = 0; }
#pragma unroll 8
  for (int j = 0; j < TCH; ++j) {
    float4 t = tile[j];
#pragma unroll
    for (int k = 0; k < P; ++k) {
      float v = fmaf(nx[k], t.x, fmaf(ny[k], t.y, fmaf(nz[k], t.z, t.w)));
      bool lt = v < best[k];
      best[k] = lt ? v : best[k];
      bidx[k] = lt ? kc*TCH + j : bidx[k];
    }
  }
#pragma unroll
  for (int k = 0; k < P; ++k) {
    int n = n0 + k*BLOCK;
    ws[OFF_ND + (size_t)(b*KCH + kc)*NN_ + n] = best[k];
    ((int*)ws)[OFF_NI + (size_t)(b*KCH + kc)*NN_ + n] = bidx[k];
  }
}

// ----------------------------------------- NN pass 2: combine + 12-sums ---
// grid (SCH, B). Combines KCH candidates per point, gathers correspondence,
// reduces [t, s(x)t] partials per (b, chunk).
__global__ __launch_bounds__(BLOCK) void icp_nn2(const float* __restrict__ src,
                                                 const float* __restrict__ tgt,
                                                 float* __restrict__ ws) {
  __shared__ float red[4*12];
  int b = blockIdx.y, c4 = blockIdx.x, tid = threadIdx.x;
  float acc[12];
#pragma unroll
  for (int c = 0; c < 12; ++c) acc[c] = 0.f;
  const int* wsI = (const int*)ws;
  for (int k = 0; k < P; ++k) {
    int n = c4 * (BLOCK*P) + tid + k*BLOCK;
    float bd = INFINITY; int bi = 0;
#pragma unroll
    for (int c = 0; c < KCH; ++c) {
      float d = ws[OFF_ND + (size_t)(b*KCH + c)*NN_ + n];
      int  id = wsI[OFF_NI + (size_t)(b*KCH + c)*NN_ + n];
      bool lt = d < bd;
      bd = lt ? d : bd;
      bi = lt ? id : bi;
    }
    const float* tp = tgt + ((size_t)b * MM_ + bi) * 3;
    const float* sp = src + ((size_t)b * NN_ + n) * 3;
    float tx = tp[0], ty = tp[1], tz = tp[2];
    float sx = sp[0], sy = sp[1], sz = sp[2];
    acc[0] += tx; acc[1] += ty; acc[2] += tz;
    acc[3] += sx*tx; acc[4] += sx*ty; acc[5] += sx*tz;
    acc[6] += sy*tx; acc[7] += sy*ty; acc[8] += sy*tz;
    acc[9] += sz*tx; acc[10] += sz*ty; acc[11] += sz*tz;
  }
#pragma unroll
  for (int c = 0; c < 12; ++c)
    for (int m = 32; m; m >>= 1) acc[c] += __shfl_xor(acc[c], m);
  int wave = tid >> 6;
  if ((tid & 63) == 0) {
#pragma unroll
    for (int c = 0; c < 12; ++c) red[wave*12 + c] = acc[c];
  }
  __syncthreads();
  if (tid < 12) {
    float s = red[tid] + red[12+tid] + red[24+tid] + red[36+tid];
    ws[OFF_PART + (b*SCH + c4)*12 + tid] = s;
  }
}

// ------------------------------------------------------------- Umeyama ----
__global__ __launch_bounds__(64) void icp_umeyama(float* __restrict__ ws) {
  int b = blockIdx.x, tid = threadIdx.x;
  __shared__ double sums[12];
  if (tid < 12) {
    double s = 0.0;
    for (int j = 0; j < SCH; ++j)
      s += (double)ws[OFF_PART + (b*SCH + j)*12 + tid];
    sums[tid] = s;
  }
  __syncthreads();
  if (tid != 0) return;

  const float* st = ws + OFF_STATS + b*4;
  const double N = (double)NN_;
  double mus[3] = {st[0]/N, st[1]/N, st[2]/N};
  double var_src = (double)st[3] - N*(mus[0]*mus[0] + mus[1]*mus[1] + mus[2]*mus[2]);
  double mut[3] = {sums[0]/N, sums[1]/N, sums[2]/N};
  double H[3][3];
  for (int d = 0; d < 3; ++d)
    for (int e = 0; e < 3; ++e)
      H[d][e] = sums[3 + 3*d + e] - N*mus[d]*mut[e];

  double A[3][3];
  for (int i = 0; i < 3; ++i)
    for (int j = 0; j < 3; ++j)
      A[i][j] = H[0][i]*H[0][j] + H[1][i]*H[1][j] + H[2][i]*H[2][j];
  double V[3][3] = {{1,0,0},{0,1,0},{0,0,1}};
  const int PP[3] = {0,0,1}, QQ[3] = {1,2,2};
  for (int sweep = 0; sweep < 14; ++sweep) {
    for (int r = 0; r < 3; ++r) {
      int p = PP[r], q = QQ[r];
      double apq = A[p][q];
      if (fabs(apq) < 1e-300) continue;
      double tau = (A[q][q] - A[p][p]) / (2.0*apq);
      double tt = (tau >= 0.0 ? 1.0 : -1.0) / (fabs(tau) + sqrt(1.0 + tau*tau));
      double c = 1.0 / sqrt(1.0 + tt*tt), s = tt*c;
      for (int k = 0; k < 3; ++k) { double akp=A[k][p], akq=A[k][q];
        A[k][p]=c*akp - s*akq; A[k][q]=s*akp + c*akq; }
      for (int k = 0; k < 3; ++k) { double apk=A[p][k], aqk=A[q][k];
        A[p][k]=c*apk - s*aqk; A[q][k]=s*apk + c*aqk; }
      for (int k = 0; k < 3; ++k) { double vkp=V[k][p], vkq=V[k][q];
        V[k][p]=c*vkp - s*vkq; V[k][q]=s*vkp + c*vkq; }
    }
  }
  double lam[3] = {A[0][0], A[1][1], A[2][2]};
  int o[3] = {0,1,2};
  if (lam[o[1]] > lam[o[0]]) { int t_=o[0]; o[0]=o[1]; o[1]=t_; }
  if (lam[o[2]] > lam[o[0]]) { int t_=o[0]; o[0]=o[2]; o[2]=t_; }
  if (lam[o[2]] > lam[o[1]]) { int t_=o[1]; o[1]=o[2]; o[2]=t_; }
  double v0[3] = {V[0][o[0]], V[1][o[0]], V[2][o[0]]};
  double v1[3] = {V[0][o[1]], V[1][o[1]], V[2][o[1]]};
  double v2[3] = {V[0][o[2]], V[1][o[2]], V[2][o[2]]};

  double hv0[3], hv1[3], hv2[3];
  for (int d = 0; d < 3; ++d) {
    hv0[d] = H[d][0]*v0[0] + H[d][1]*v0[1] + H[d][2]*v0[2];
    hv1[d] = H[d][0]*v1[0] + H[d][1]*v1[1] + H[d][2]*v1[2];
    hv2[d] = H[d][0]*v2[0] + H[d][1]*v2[1] + H[d][2]*v2[2];
  }
  double S0 = sqrt(hv0[0]*hv0[0] + hv0[1]*hv0[1] + hv0[2]*hv0[2]);
  double u0[3];
  double inv0 = (S0 > 1e-30) ? 1.0/S0 : 0.0;
  u0[0]=hv0[0]*inv0; u0[1]=hv0[1]*inv0; u0[2]=hv0[2]*inv0;
  if (S0 <= 1e-30) { u0[0]=1.0; u0[1]=0.0; u0[2]=0.0; }
  double S1 = sqrt(hv1[0]*hv1[0] + hv1[1]*hv1[1] + hv1[2]*hv1[2]);
  double d01 = u0[0]*hv1[0] + u0[1]*hv1[1] + u0[2]*hv1[2];
  double w1[3] = {hv1[0]-d01*u0[0], hv1[1]-d01*u0[1], hv1[2]-d01*u0[2]};
  double n1 = sqrt(w1[0]*w1[0] + w1[1]*w1[1] + w1[2]*w1[2]);
  double u1[3];
  if (n1 > 1e-30) { u1[0]=w1[0]/n1; u1[1]=w1[1]/n1; u1[2]=w1[2]/n1; }
  else {
    double ax = fabs(u0[0]);
    double t0[3] = { ax < 0.9 ? 1.0 : 0.0, ax < 0.9 ? 0.0 : 1.0, 0.0 };
    u1[0] = u0[1]*t0[2]-u0[2]*t0[1];
    u1[1] = u0[2]*t0[0]-u0[0]*t0[2];
    u1[2] = u0[0]*t0[1]-u0[1]*t0[0];
    double nn = sqrt(u1[0]*u1[0]+u1[1]*u1[1]+u1[2]*u1[2]);
    u1[0]/=nn; u1[1]/=nn; u1[2]/=nn;
  }
  double u2[3] = {u0[1]*u1[2]-u0[2]*u1[1],
                  u0[2]*u1[0]-u0[0]*u1[2],
                  u0[0]*u1[1]-u0[1]*u1[0]};
  double s2p = u2[0]*hv2[0] + u2[1]*hv2[1] + u2[2]*hv2[2];
  double dV = v0[0]*(v1[1]*v2[2]-v1[2]*v2[1])
            - v0[1]*(v1[0]*v2[2]-v1[2]*v2[0])
            + v0[2]*(v1[0]*v2[1]-v1[1]*v2[0]);
  dV = (dV >= 0.0) ? 1.0 : -1.0;
  double traceS = S0 + S1 + dV * s2p;

  double R[3][3];
  for (int i = 0; i < 3; ++i)
    for (int k = 0; k < 3; ++k)
      R[i][k] = v0[i]*u0[k] + v1[i]*u1[k] + dV*v2[i]*u2[k];

  double scale = traceS / (var_src + 1e-8);
  scale = fmin(fmax(scale, 0.5), 2.0);
  double tv[3];
  for (int e = 0; e < 3; ++e)
    tv[e] = mut[e] - scale*(R[e][0]*mus[0] + R[e][1]*mus[1] + R[e][2]*mus[2]);

  float* T = ws + OFF_T + b*16;
  for (int e = 0; e < 3; ++e)
    for (int d = 0; d < 3; ++d)
      T[3*e + d] = (float)R[e][d];
  T[9]  = (float)tv[0]; T[10] = (float)tv[1]; T[11] = (float)tv[2];
  T[12] = (float)scale;
}

// --------------------------------------------------- final src->tgt -------
// grid (SCH, KCH, B). Writes aligned (kc==0) + partial rowmin (incl. p2).
__global__ __launch_bounds__(BLOCK) void icp_s2t(const float* __restrict__ src,
                                                 const float* __restrict__ tgt,
                                                 float* __restrict__ out,
                                                 float* __restrict__ ws) {
  __shared__ float4 tile[TCH];
  int b = blockIdx.z, kc = blockIdx.y, tid = threadIdx.x;
  int n0 = blockIdx.x * (BLOCK * P) + tid;
  const float* T = ws + OFF_T + b*16;
  float sc = T[12];
  float nx[P], ny[P], nz[P], p2[P];
#pragma unroll
  for (int k = 0; k < P; ++k) {
    const float* sp = src + ((size_t)b * NN_ + n0 + k*BLOCK) * 3;
    float sx = sp[0], sy = sp[1], sz = sp[2];
    float px = fmaf(sc, fmaf(T[0], sx, fmaf(T[1], sy, T[2]*sz)), T[9]);
    float py = fmaf(sc, fmaf(T[3], sx, fmaf(T[4], sy, T[5]*sz)), T[10]);
    float pz = fmaf(sc, fmaf(T[6], sx, fmaf(T[7], sy, T[8]*sz)), T[11]);
    if (kc == 0) {
      float* op = out + 1 + ((size_t)b * NN_ + n0 + k*BLOCK) * 3;
      op[0] = px; op[1] = py; op[2] = pz;
    }
    p2[k] = fmaf(px, px, fmaf(py, py, pz*pz));
    nx[k] = -2.f*px; ny[k] = -2.f*py; nz[k] = -2.f*pz;
  }
  const float* tb = tgt + ((size_t)b * MM_ + kc * TCH) * 3;
  for (int j = tid; j < TCH; j += BLOCK) {
    float tx = tb[3*j], ty = tb[3*j+1], tz = tb[3*j+2];
    tile[j] = make_float4(tx, ty, tz, fmaf(tx, tx, fmaf(ty, ty, tz*tz)));
  }
  __syncthreads();

  float best[P];
#pragma unroll
  for (int k = 0; k < P; ++k) best[k] = INFINITY;
#pragma unroll 8
  for (int j = 0; j < TCH; ++j) {
    float4 t = tile[j];
#pragma unroll
    for (int k = 0; k < P; ++k) {
      float v = fmaf(nx[k], t.x, fmaf(ny[k], t.y, fmaf(nz[k], t.z, t.w)));
      best[k] = fminf(best[k], v);
    }
  }
#pragma unroll
  for (int k = 0; k < P; ++k)
    ws[OFF_FA + (size_t)(b*KCH + kc)*NN_ + n0 + k*BLOCK] = best[k] + p2[k];
}

// --------------------------------------------------- final tgt->src -------
// grid (SCH, KCH, B). Queries = target points; searches aligned (from out).
__global__ __launch_bounds__(BLOCK) void icp_t2s(const float* __restrict__ tgt,
                                                 const float* __restrict__ out,
                                                 float* __restrict__ ws) {
  __shared__ float4 tile[TCH];
  int b = blockIdx.z, kc = blockIdx.y, tid = threadIdx.x;
  int m0 = blockIdx.x * (BLOCK * P) + tid;
  float nx[P], ny[P], nz[P], q2[P];
#pragma unroll
  for (int k = 0; k < P; ++k) {
    const float* qp = tgt + ((size_t)b * MM_ + m0 + k*BLOCK) * 3;
    float qx = qp[0], qy = qp[1], qz = qp[2];
    q2[k] = fmaf(qx, qx, fmaf(qy, qy, qz*qz));
    nx[k] = -2.f*qx; ny[k] = -2.f*qy; nz[k] = -2.f*qz;
  }
  const float* ab = out + 1 + ((size_t)b * NN_ + kc * TCH) * 3;
  for (int j = tid; j < TCH; j += BLOCK) {
    float ax = ab[3*j], ay = ab[3*j+1], az = ab[3*j+2];
    tile[j] = make_float4(ax, ay, az, fmaf(ax, ax, fmaf(ay, ay, az*az)));
  }
  __syncthreads();

  float best[P];
#pragma unroll
  for (int k = 0; k < P; ++k) best[k] = INFINITY;
#pragma unroll 8
  for (int j = 0; j < TCH; ++j) {
    float4 a = tile[j];
#pragma unroll
    for (int k = 0; k < P; ++k) {
      float v = fmaf(nx[k], a.x, fmaf(ny[k], a.y, fmaf(nz[k], a.z, a.w)));
      best[k] = fminf(best[k], v);
    }
  }
#pragma unroll
  for (int k = 0; k < P; ++k)
    ws[OFF_FB + (size_t)(b*KCH + kc)*MM_ + m0 + k*BLOCK] = best[k] + q2[k];
}

// ------------------------------------------- final combine + per-batch ----
__global__ __launch_bounds__(BLOCK) void icp_fcomb(float* __restrict__ ws) {
  __shared__ float red[4*2];
  int b = blockIdx.x, tid = threadIdx.x;
  float sa = 0.f, sb = 0.f;
  for (int k = 0; k < NN_/BLOCK; ++k) {
    int n = tid + k*BLOCK;
    float m1 = INFINITY, m2 = INFINITY;
#pragma unroll
    for (int c = 0; c < KCH; ++c) {
      m1 = fminf(m1, ws[OFF_FA + (size_t)(b*KCH + c)*NN_ + n]);
      m2 = fminf(m2, ws[OFF_FB + (size_t)(b*KCH + c)*MM_ + n]);
    }
    sa += fmaxf(m1, 0.f);
    sb += fmaxf(m2, 0.f);
  }
  for (int m = 32; m; m >>= 1) {
    sa += __shfl_xor(sa, m); sb += __shfl_xor(sb, m);
  }
  int wave = tid >> 6;
  if ((tid & 63) == 0) { red[wave*2] = sa; red[wave*2+1] = sb; }
  __syncthreads();
  if (tid == 0) {
    sa = red[0] + red[2] + red[4] + red[6];
    sb = red[1] + red[3] + red[5] + red[7];
    ws[OFF_CH + b] = sa / (float)NN_ + sb / (float)MM_;
  }
}

// ------------------------------------------------------------ finalize ----
__global__ __launch_bounds__(64) void icp_finalize(float* __restrict__ out,
                                                   const float* __restrict__ ws) {
  if (threadIdx.x == 0) {
    float s = 0.f;
    for (int b = 0; b < NB; ++b) s += ws[OFF_CH + b];
    out[0] = s / (float)NB;
  }
}

// -------------------------------------------------------------- launch ----
extern "C" void kernel_launch(void* const* d_in, const int* in_sizes, int n_in,
                              void* d_out, int out_size, void* d_ws, size_t ws_size,
                              hipStream_t stream) {
  const float* src = (const float*)d_in[0];
  const float* tgt = (const float*)d_in[1];
  float* out = (float*)d_out;
  float* ws  = (float*)d_ws;

  icp_init<<<NB, BLOCK, 0, stream>>>(src, ws);
  for (int it = 0; it < NITER; ++it) {
    icp_nn1<<<dim3(SCH, KCH, NB), BLOCK, 0, stream>>>(src, tgt, ws);
    icp_nn2<<<dim3(SCH, NB), BLOCK, 0, stream>>>(src, tgt, ws);
    icp_umeyama<<<NB, 64, 0, stream>>>(ws);
  }
  icp_s2t<<<dim3(SCH, KCH, NB), BLOCK, 0, stream>>>(src, tgt, out, ws);
  icp_t2s<<<dim3(SCH, KCH, NB), BLOCK, 0, stream>>>(tgt, out, ws);
  icp_fcomb<<<NB, BLOCK, 0, stream>>>(ws);
  icp_finalize<<<1, 64, 0, stream>>>(out, ws);
}